// Round 1
// baseline (2623.542 us; speedup 1.0000x reference)
//
#include <hip/hip_runtime.h>
#include <hip/hip_bf16.h>

// CustomWindowMHA on MI355X.
// x:(2,2048,1024) f32, qkv:(3072,1024) f32, wo:(1024,1024) f32 -> out:(2,2048,1024) f32
// Strategy: split-fp32 (hi/lo bf16) MFMA GEMMs with K'=3*1024 = hihi+hilo+lohi,
// fp32 sparse attention (window 128 + dilation 4).

typedef short bf16x8 __attribute__((ext_vector_type(8)));
typedef float f32x4 __attribute__((ext_vector_type(4)));

#define K3 3072

__device__ __forceinline__ unsigned short f2bf(float f){
  unsigned u = __float_as_uint(f);
  u += 0x7FFFu + ((u >> 16) & 1u);           // RNE
  return (unsigned short)(u >> 16);
}
__device__ __forceinline__ float bf2f(unsigned short h){
  return __uint_as_float(((unsigned)h) << 16);
}

// fp32 row (width 1024) -> bf16 row (width 3072).
// ASIDE=1: [hi|hi|lo]   (left operand of C = A·B^T)
// ASIDE=0: [hi|lo|hi]   (right operand)
template<int ASIDE>
__global__ void split_kernel(const float* __restrict__ src,
                             unsigned short* __restrict__ dst, int total){
  int idx = blockIdx.x * 256 + threadIdx.x;
  if (idx >= total) return;
  int m = idx >> 10;
  int c = idx & 1023;
  float v = src[idx];
  unsigned short hi = f2bf(v);
  unsigned short lo = f2bf(v - bf2f(hi));
  unsigned short* row = dst + (size_t)m * K3;
  if (ASIDE){ row[c] = hi; row[1024 + c] = hi; row[2048 + c] = lo; }
  else      { row[c] = hi; row[1024 + c] = lo; row[2048 + c] = hi; }
}

// C[m][n] = sum_k A[m][k]*B[n][k], A:(M x 3072), B:(N x 3072) bf16, C fp32 (ldc).
// 128x128 tile, BK=64, 4 waves (2x2 of 64x64), mfma_f32_16x16x32_bf16.
// LDS XOR-swizzled (byte ^= (row&7)<<4) -> ~2-way bank conflicts on ds_read_b128.
__global__ __launch_bounds__(256)
void gemm_nt(const unsigned short* __restrict__ A, const unsigned short* __restrict__ B,
             float* __restrict__ C, int ldc){
  __shared__ __align__(16) unsigned short sMem[2 * 128 * 64];
  char* sAb = (char*)sMem;
  char* sBb = (char*)(sMem + 128 * 64);

  const int tid  = threadIdx.x;
  const int lane = tid & 63;
  const int wave = tid >> 6;
  const int wr = wave >> 1, wc = wave & 1;
  const size_t m0 = (size_t)blockIdx.x * 128;
  const size_t n0 = (size_t)blockIdx.y * 128;

  // staging: each thread owns 64B of A-tile and 64B of B-tile per K-step
  const int sr = tid >> 1;              // tile row 0..127
  const int sc = (tid & 1) * 32;        // elem col 0 or 32
  const unsigned short* gA = A + (m0 + sr) * K3 + sc;
  const unsigned short* gB = B + (n0 + sr) * K3 + sc;
  int stOff[4];
  #pragma unroll
  for (int q = 0; q < 4; q++)
    stOff[q] = sr * 128 + ((sc * 2 + q * 16) ^ ((sr & 7) << 4));

  // fragment read addressing (A row / B row = lane&15, k-group = lane>>4)
  const int fr = lane & 15;
  const int kg = lane >> 4;
  const int xr = (fr & 7) << 4;
  const int aBase = (wr * 64 + fr) * 128;
  const int bBase = (wc * 64 + fr) * 128;

  f32x4 acc[4][4] = {};
  bf16x8 ra[4], rb[4];

  // prologue: tile 0
  #pragma unroll
  for (int q = 0; q < 4; q++){
    ra[q] = *(const bf16x8*)(gA + q * 8);
    rb[q] = *(const bf16x8*)(gB + q * 8);
  }
  #pragma unroll
  for (int q = 0; q < 4; q++){
    *(bf16x8*)(sAb + stOff[q]) = ra[q];
    *(bf16x8*)(sBb + stOff[q]) = rb[q];
  }
  __syncthreads();

  const int NT = K3 / 64;
  for (int t = 0; t < NT; t++){
    if (t + 1 < NT){
      const unsigned short* pA = gA + (t + 1) * 64;
      const unsigned short* pB = gB + (t + 1) * 64;
      #pragma unroll
      for (int q = 0; q < 4; q++){
        ra[q] = *(const bf16x8*)(pA + q * 8);
        rb[q] = *(const bf16x8*)(pB + q * 8);
      }
    }
    #pragma unroll
    for (int ks = 0; ks < 2; ks++){
      bf16x8 af[4], bfr[4];
      const int cb = (ks * 64 + kg * 16) ^ xr;
      #pragma unroll
      for (int f = 0; f < 4; f++){
        af[f]  = *(const bf16x8*)(sAb + aBase + f * 2048 + cb);
        bfr[f] = *(const bf16x8*)(sBb + bBase + f * 2048 + cb);
      }
      #pragma unroll
      for (int fm = 0; fm < 4; fm++)
        #pragma unroll
        for (int fn = 0; fn < 4; fn++)
          acc[fm][fn] = __builtin_amdgcn_mfma_f32_16x16x32_bf16(af[fm], bfr[fn], acc[fm][fn], 0, 0, 0);
    }
    __syncthreads();
    if (t + 1 < NT){
      #pragma unroll
      for (int q = 0; q < 4; q++){
        *(bf16x8*)(sAb + stOff[q]) = ra[q];
        *(bf16x8*)(sBb + stOff[q]) = rb[q];
      }
      __syncthreads();
    }
  }

  // C/D layout (verified m89): col = lane&15, row = (lane>>4)*4 + reg
  const int crow = wr * 64 + (lane >> 4) * 4;
  const int ccol = wc * 64 + (lane & 15);
  #pragma unroll
  for (int fm = 0; fm < 4; fm++)
    #pragma unroll
    for (int fn = 0; fn < 4; fn++){
      #pragma unroll
      for (int i2 = 0; i2 < 4; i2++){
        size_t r = m0 + crow + fm * 16 + i2;
        size_t c = n0 + ccol + fn * 16;
        C[r * ldc + c] = acc[fm][fn][i2];
      }
    }
}

// Sparse attention, fp32. One block (128 thr) per (b,h,i).
// QKV: (4096 x 3072) fp32 rows [Q | K | V]. Output written as split bf16 [hi|hi|lo].
__global__ __launch_bounds__(128)
void attn_kernel(const float* __restrict__ QKV, unsigned short* __restrict__ AttnP){
  const int i   = blockIdx.x;
  const int b   = blockIdx.y >> 4;
  const int h   = blockIdx.y & 15;
  const int tid = threadIdx.x;

  __shared__ float q[64];
  __shared__ float s[608];
  __shared__ float red[132];

  const float* base = QKV + (size_t)b * 2048 * K3;
  if (tid < 64) q[tid] = base[(size_t)i * K3 + h * 64 + tid] * 0.125f; // 1/sqrt(64)

  const int nw = min(i + 1, 128);
  const int j0 = i - nw + 1;
  const int nd = (i >= 132) ? (((i - 132) >> 2) + 1) : 0;
  const int n  = nw + nd;
  __syncthreads();

  // scores: thread t handles allowed index t, t+128, ...
  for (int t = tid; t < n; t += 128){
    int j = (t < nw) ? (j0 + t) : (i - 132 - ((t - nw) << 2));
    const float* kr = base + (size_t)j * K3 + 1024 + h * 64;
    float acc = 0.f;
    #pragma unroll
    for (int d = 0; d < 64; d += 4){
      float4 kv = *(const float4*)(kr + d);
      acc = fmaf(q[d],     kv.x, acc);
      acc = fmaf(q[d + 1], kv.y, acc);
      acc = fmaf(q[d + 2], kv.z, acc);
      acc = fmaf(q[d + 3], kv.w, acc);
    }
    s[t] = acc;
  }
  __syncthreads();

  // softmax (2-wave block reduce)
  float mx = -1e30f;
  for (int t = tid; t < n; t += 128) mx = fmaxf(mx, s[t]);
  #pragma unroll
  for (int o = 32; o >= 1; o >>= 1) mx = fmaxf(mx, __shfl_xor(mx, o, 64));
  if ((tid & 63) == 0) red[128 + (tid >> 6)] = mx;
  __syncthreads();
  mx = fmaxf(red[128], red[129]);

  float sum = 0.f;
  for (int t = tid; t < n; t += 128){
    float e = __expf(s[t] - mx);
    s[t] = e;
    sum += e;
  }
  #pragma unroll
  for (int o = 32; o >= 1; o >>= 1) sum += __shfl_xor(sum, o, 64);
  if ((tid & 63) == 0) red[130 + (tid >> 6)] = sum;
  __syncthreads();
  const float inv = 1.f / (red[130] + red[131]);

  // PV: d = tid&63, two j-halves
  const int d    = tid & 63;
  const int half = tid >> 6;
  float acc = 0.f;
  for (int t = half; t < n; t += 2){
    int j = (t < nw) ? (j0 + t) : (i - 132 - ((t - nw) << 2));
    acc = fmaf(s[t], base[(size_t)j * K3 + 2048 + h * 64 + d], acc);
  }
  red[tid] = acc;
  __syncthreads();
  if (tid < 64){
    float o = (red[tid] + red[tid + 64]) * inv;
    unsigned short hi = f2bf(o);
    unsigned short lo = f2bf(o - bf2f(hi));
    unsigned short* row = AttnP + ((size_t)(b * 2048 + i)) * K3;
    int c = h * 64 + tid;
    row[c] = hi; row[1024 + c] = hi; row[2048 + c] = lo;
  }
}

extern "C" void kernel_launch(void* const* d_in, const int* in_sizes, int n_in,
                              void* d_out, int out_size, void* d_ws, size_t ws_size,
                              hipStream_t stream){
  const float* x   = (const float*)d_in[0];
  const float* qkv = (const float*)d_in[1];
  const float* wo  = (const float*)d_in[2];
  float* out = (float*)d_out;

  // workspace layout (needs 120 MB):
  // Ap    @ 0         : 4096x3072 bf16 (24 MB)  x split [hi|hi|lo]
  // Bp    @ 24 MB     : 3072x3072 bf16 (18 MB)  qkv split [hi|lo|hi]
  // Wp    @ 42 MB     : 1024x3072 bf16 (6 MB)   wo split [hi|lo|hi]
  // QKVb  @ 48 MB     : 4096x3072 f32  (48 MB)
  // AttnP @ 96 MB     : 4096x3072 bf16 (24 MB)  attn out split [hi|hi|lo]
  char* ws = (char*)d_ws;
  unsigned short* Ap    = (unsigned short*)(ws);
  unsigned short* Bp    = (unsigned short*)(ws + 25165824);
  unsigned short* Wp    = (unsigned short*)(ws + 44040192);
  float*          QKVb  = (float*)(ws + 50331648);
  unsigned short* AttnP = (unsigned short*)(ws + 100663296);

  split_kernel<1><<<dim3(16384), dim3(256), 0, stream>>>(x,   Ap, 4096 * 1024);
  split_kernel<0><<<dim3(12288), dim3(256), 0, stream>>>(qkv, Bp, 3072 * 1024);
  split_kernel<0><<<dim3(4096),  dim3(256), 0, stream>>>(wo,  Wp, 1024 * 1024);

  gemm_nt<<<dim3(32, 24), dim3(256), 0, stream>>>(Ap, Bp, QKVb, 3072);
  attn_kernel<<<dim3(2048, 32), dim3(128), 0, stream>>>(QKVb, AttnP);
  gemm_nt<<<dim3(32, 8), dim3(256), 0, stream>>>(AttnP, Wp, out, 1024);
}

// Round 2
// 262.527 us; speedup vs baseline: 9.9934x; 9.9934x over previous
//
#include <hip/hip_runtime.h>
#include <hip/hip_bf16.h>

// CustomWindowMHA on MI355X.
// x:(2,2048,1024) f32, qkv:(3072,1024) f32, wo:(1024,1024) f32 -> out:(2,2048,1024) f32
// Pipeline:
//   cvt x,qkv -> bf16 ; wo -> split [hi|lo|hi] (K'=3072)
//   GEMM1 (bf16, K=1024): epilogue scatters bf16 Q(*0.125), K, K_dil(residue-compacted),
//                         V^T, V^T_dil(residue-compacted)
//   attn: block-sparse MFMA flash attention, 1 wave / 32 residue-grouped queries
//         -> AttnP split bf16 [hi|hi|lo]
//   GEMM2 (split bf16, K=3072) -> out f32

typedef short bf16x8 __attribute__((ext_vector_type(8)));
typedef float f32x4 __attribute__((ext_vector_type(4)));
typedef unsigned short us4 __attribute__((ext_vector_type(4)));

__device__ __forceinline__ unsigned short f2bf(float f){
  unsigned u = __float_as_uint(f);
  u += 0x7FFFu + ((u >> 16) & 1u);           // RNE
  return (unsigned short)(u >> 16);
}
__device__ __forceinline__ float bf2f(unsigned short h){
  return __uint_as_float(((unsigned)h) << 16);
}

// ---------------- converts ----------------
__global__ void cvt_bf16_kernel(const float* __restrict__ src,
                                unsigned short* __restrict__ dst, int n4){
  int idx = blockIdx.x * 256 + threadIdx.x;
  if (idx >= n4) return;
  float4 v = ((const float4*)src)[idx];
  us4 o;
  o[0] = f2bf(v.x); o[1] = f2bf(v.y); o[2] = f2bf(v.z); o[3] = f2bf(v.w);
  ((us4*)dst)[idx] = o;
}

// fp32 row (1024) -> split bf16 row (3072), [hi|lo|hi] (right operand)
__global__ void split_kernel(const float* __restrict__ src,
                             unsigned short* __restrict__ dst, int total){
  int idx = blockIdx.x * 256 + threadIdx.x;
  if (idx >= total) return;
  int m = idx >> 10;
  int c = idx & 1023;
  float v = src[idx];
  unsigned short hi = f2bf(v);
  unsigned short lo = f2bf(v - bf2f(hi));
  unsigned short* row = dst + (size_t)m * 3072;
  row[c] = hi; row[1024 + c] = lo; row[2048 + c] = hi;
}

// ---------------- GEMM ----------------
// C[m][n] = sum_k A[m][k]*B[n][k], A:(M x KDIM), B:(N x KDIM) bf16.
// EPI=0: plain f32 C (ldc). EPI=1: QKV scatter epilogue (bf16 Q/K/Kd/Vt/Vtd).
template<int KDIM, int EPI>
__global__ __launch_bounds__(256)
void gemm_nt(const unsigned short* __restrict__ A, const unsigned short* __restrict__ B,
             float* __restrict__ C, int ldc,
             unsigned short* __restrict__ Qb, unsigned short* __restrict__ Kb,
             unsigned short* __restrict__ Kd, unsigned short* __restrict__ Vt,
             unsigned short* __restrict__ Vtd){
  __shared__ __align__(16) unsigned short sMem[2 * 128 * 64];
  char* sAb = (char*)sMem;
  char* sBb = (char*)(sMem + 128 * 64);

  const int tid  = threadIdx.x;
  const int lane = tid & 63;
  const int wave = tid >> 6;
  const int wr = wave >> 1, wc = wave & 1;
  const size_t m0 = (size_t)blockIdx.x * 128;
  const size_t n0 = (size_t)blockIdx.y * 128;

  const int sr = tid >> 1;
  const int sc = (tid & 1) * 32;
  const unsigned short* gA = A + (m0 + sr) * KDIM + sc;
  const unsigned short* gB = B + (n0 + sr) * KDIM + sc;
  int stOff[4];
  #pragma unroll
  for (int q = 0; q < 4; q++)
    stOff[q] = sr * 128 + ((sc * 2 + q * 16) ^ ((sr & 7) << 4));

  const int fr = lane & 15;
  const int kg = lane >> 4;
  const int xr = (fr & 7) << 4;
  const int aBase = (wr * 64 + fr) * 128;
  const int bBase = (wc * 64 + fr) * 128;

  f32x4 acc[4][4] = {};
  bf16x8 ra[4], rb[4];

  #pragma unroll
  for (int q = 0; q < 4; q++){
    ra[q] = *(const bf16x8*)(gA + q * 8);
    rb[q] = *(const bf16x8*)(gB + q * 8);
  }
  #pragma unroll
  for (int q = 0; q < 4; q++){
    *(bf16x8*)(sAb + stOff[q]) = ra[q];
    *(bf16x8*)(sBb + stOff[q]) = rb[q];
  }
  __syncthreads();

  const int NT = KDIM / 64;
  for (int t = 0; t < NT; t++){
    if (t + 1 < NT){
      const unsigned short* pA = gA + (t + 1) * 64;
      const unsigned short* pB = gB + (t + 1) * 64;
      #pragma unroll
      for (int q = 0; q < 4; q++){
        ra[q] = *(const bf16x8*)(pA + q * 8);
        rb[q] = *(const bf16x8*)(pB + q * 8);
      }
    }
    #pragma unroll
    for (int ks = 0; ks < 2; ks++){
      bf16x8 af[4], bfr[4];
      const int cb = (ks * 64 + kg * 16) ^ xr;
      #pragma unroll
      for (int f = 0; f < 4; f++){
        af[f]  = *(const bf16x8*)(sAb + aBase + f * 2048 + cb);
        bfr[f] = *(const bf16x8*)(sBb + bBase + f * 2048 + cb);
      }
      #pragma unroll
      for (int fm = 0; fm < 4; fm++)
        #pragma unroll
        for (int fn = 0; fn < 4; fn++)
          acc[fm][fn] = __builtin_amdgcn_mfma_f32_16x16x32_bf16(af[fm], bfr[fn], acc[fm][fn], 0, 0, 0);
    }
    __syncthreads();
    if (t + 1 < NT){
      #pragma unroll
      for (int q = 0; q < 4; q++){
        *(bf16x8*)(sAb + stOff[q]) = ra[q];
        *(bf16x8*)(sBb + stOff[q]) = rb[q];
      }
      __syncthreads();
    }
  }

  // C/D layout (verified): col = lane&15, row = (lane>>4)*4 + reg
  const int crow = wr * 64 + (lane >> 4) * 4;
  const int ccol = wc * 64 + (lane & 15);
  if constexpr (EPI == 0){
    #pragma unroll
    for (int fm = 0; fm < 4; fm++)
      #pragma unroll
      for (int fn = 0; fn < 4; fn++)
        #pragma unroll
        for (int i2 = 0; i2 < 4; i2++){
          size_t r = m0 + crow + fm * 16 + i2;
          size_t c = n0 + ccol + fn * 16;
          C[r * ldc + c] = acc[fm][fn][i2];
        }
  } else {
    const int r15 = lane & 15;
    #pragma unroll
    for (int fn = 0; fn < 4; fn++){
      const int nb = (int)n0 + wc * 64 + 16 * fn;  // wave-uniform
      const int which = nb >> 10;                   // 0=Q 1=K 2=V
      const int hh = (nb >> 6) & 15;
      const int d = (nb & 63) + r15;
      #pragma unroll
      for (int fm = 0; fm < 4; fm++)
        #pragma unroll
        for (int i2 = 0; i2 < 4; i2++){
          const int token = (int)m0 + crow + fm * 16 + i2;
          const int btok = token >> 11;
          const int itok = token & 2047;
          const int bhh = btok * 16 + hh;
          const float val = acc[fm][fn][i2];
          if (which == 0){
            Qb[((size_t)bhh * 2048 + itok) * 64 + d] = f2bf(val * 0.125f);
          } else if (which == 1){
            const unsigned short v = f2bf(val);
            Kb[((size_t)bhh * 2048 + itok) * 64 + d] = v;
            Kd[(((size_t)bhh * 4 + (itok & 3)) * 512 + (itok >> 2)) * 64 + d] = v;
          } else {
            const unsigned short v = f2bf(val);
            Vt[((size_t)bhh * 64 + d) * 2048 + itok] = v;
            Vtd[(((size_t)bhh * 4 + (itok & 3)) * 64 + d) * 512 + (itok >> 2)] = v;
          }
        }
    }
  }
}

// ---------------- block-sparse MFMA flash attention ----------------
// One wave per (b,h, residue c, group g): 32 queries i = c + 128*g + 4*t, t=0..31.
// Dilated keys j=4m+c come from residue-compacted Kd/Vtd (contiguous m-tiles 0..g-1);
// window keys from natural Kb/Vt (tiles jt0..jt1, per-element masked).
__global__ __launch_bounds__(64)
void attn_mfma(const unsigned short* __restrict__ Qb,
               const unsigned short* __restrict__ Kb,
               const unsigned short* __restrict__ Kd,
               const unsigned short* __restrict__ Vt,
               const unsigned short* __restrict__ Vtd,
               unsigned short* __restrict__ AttnP){
  const int lane = threadIdx.x;
  const int r15 = lane & 15;
  const int g   = lane >> 4;
  const int c   = blockIdx.x & 3;
  const int gq  = 15 - (blockIdx.x >> 2);   // heavy blocks first
  const int bh  = blockIdx.y;
  const int b   = bh >> 4;
  const int h   = bh & 15;

  __shared__ __align__(16) unsigned short P_lds[32 * 40]; // row stride 40 hw (80B)
  __shared__ __align__(16) float sc_lds[32];

  const int i_min = c + 128 * gq;

  const unsigned short* Qb_b  = Qb  + (size_t)bh * 2048 * 64;
  const unsigned short* Kb_b  = Kb  + (size_t)bh * 2048 * 64;
  const unsigned short* Vt_b  = Vt  + (size_t)bh * 64 * 2048;
  const unsigned short* Kd_b  = Kd  + ((size_t)bh * 4 + c) * (512 * 64);
  const unsigned short* Vtd_b = Vtd + ((size_t)bh * 4 + c) * (64 * 512);

  // Q fragments (B-operand; swapped QK^T): q row = r15+16fc, d-chunk = 8g+32kc
  bf16x8 qf[2][2];
  #pragma unroll
  for (int fc = 0; fc < 2; fc++){
    const int i = i_min + 4 * (r15 + 16 * fc);
    #pragma unroll
    for (int kc = 0; kc < 2; kc++)
      qf[fc][kc] = *(const bf16x8*)(Qb_b + (size_t)i * 64 + 32 * kc + 8 * g);
  }

  float mrow[2] = {-1e30f, -1e30f};
  float lrow[2] = {0.f, 0.f};
  f32x4 acc[2][4] = {};   // [fq][fd]: row q = 16fq+4g+reg, col d = r15+16fd

  const int jt0 = (i_min > 127) ? ((i_min - 127) >> 5) : 0;
  const int jt1 = (i_min + 124) >> 5;
  const int ntiles = gq + (jt1 - jt0 + 1);

  for (int tt = 0; tt < ntiles; tt++){
    const bool dil = (tt < gq);
    bf16x8 ka[2][2], vb[4];
    int kbase;
    if (dil){
      const int m0 = 32 * tt;
      kbase = m0;
      #pragma unroll
      for (int fr2 = 0; fr2 < 2; fr2++){
        const size_t row = (size_t)(m0 + 16 * fr2 + r15);
        #pragma unroll
        for (int kc = 0; kc < 2; kc++)
          ka[fr2][kc] = *(const bf16x8*)(Kd_b + row * 64 + 32 * kc + 8 * g);
      }
      #pragma unroll
      for (int fd = 0; fd < 4; fd++)
        vb[fd] = *(const bf16x8*)(Vtd_b + (size_t)(r15 + 16 * fd) * 512 + m0 + 8 * g);
    } else {
      const int j0 = 32 * (jt0 + tt - gq);
      kbase = j0;
      #pragma unroll
      for (int fr2 = 0; fr2 < 2; fr2++){
        const size_t row = (size_t)(j0 + 16 * fr2 + r15);
        #pragma unroll
        for (int kc = 0; kc < 2; kc++)
          ka[fr2][kc] = *(const bf16x8*)(Kb_b + row * 64 + 32 * kc + 8 * g);
      }
      #pragma unroll
      for (int fd = 0; fd < 4; fd++)
        vb[fd] = *(const bf16x8*)(Vt_b + (size_t)(r15 + 16 * fd) * 2048 + j0 + 8 * g);
    }

    // QK^T swapped: D[key][query]; key = 16fr+4g+reg, query = r15+16fc
    f32x4 sf[2][2];
    #pragma unroll
    for (int fr2 = 0; fr2 < 2; fr2++)
      #pragma unroll
      for (int fc = 0; fc < 2; fc++){
        f32x4 z = {0.f, 0.f, 0.f, 0.f};
        z = __builtin_amdgcn_mfma_f32_16x16x32_bf16(ka[fr2][0], qf[fc][0], z, 0, 0, 0);
        z = __builtin_amdgcn_mfma_f32_16x16x32_bf16(ka[fr2][1], qf[fc][1], z, 0, 0, 0);
        sf[fr2][fc] = z;
      }

    // masking
    const bool needmask = dil ? (tt == gq - 1) : true;
    if (needmask){
      #pragma unroll
      for (int fr2 = 0; fr2 < 2; fr2++)
        #pragma unroll
        for (int rr = 0; rr < 4; rr++){
          const int kl = kbase + 16 * fr2 + 4 * g + rr;
          #pragma unroll
          for (int fc = 0; fc < 2; fc++){
            const int t = r15 + 16 * fc;
            bool ok;
            if (dil) ok = (kl <= 32 * gq + t - 33);
            else { const int i = i_min + 4 * t; ok = (kl <= i) && (kl >= i - 127); }
            if (!ok) sf[fr2][fc][rr] = -1e30f;
          }
        }
    }

    // online softmax per query (column)
    float pp[2][2][4];
    #pragma unroll
    for (int fc = 0; fc < 2; fc++){
      float mx = sf[0][fc][0];
      #pragma unroll
      for (int fr2 = 0; fr2 < 2; fr2++)
        #pragma unroll
        for (int rr = 0; rr < 4; rr++) mx = fmaxf(mx, sf[fr2][fc][rr]);
      mx = fmaxf(mx, __shfl_xor(mx, 16));
      mx = fmaxf(mx, __shfl_xor(mx, 32));
      const float mn = fmaxf(mrow[fc], mx);
      const float kill = (mn > -1e29f) ? 1.f : 0.f;  // no key seen yet -> zero everything
      const float scf = __expf(mrow[fc] - mn);
      mrow[fc] = mn;
      float rs = 0.f;
      #pragma unroll
      for (int fr2 = 0; fr2 < 2; fr2++)
        #pragma unroll
        for (int rr = 0; rr < 4; rr++){
          const float pv = __expf(sf[fr2][fc][rr] - mn) * kill;
          pp[fr2][fc][rr] = pv;
          rs += pv;
        }
      rs += __shfl_xor(rs, 16);
      rs += __shfl_xor(rs, 32);
      lrow[fc] = lrow[fc] * scf + rs;
      if (g == 0) sc_lds[r15 + 16 * fc] = scf;
    }

    // P -> LDS (bf16), row q, cols 16fr+4g+0..3
    #pragma unroll
    for (int fc = 0; fc < 2; fc++){
      const int q = r15 + 16 * fc;
      #pragma unroll
      for (int fr2 = 0; fr2 < 2; fr2++){
        us4 w;
        w[0] = f2bf(pp[fr2][fc][0]); w[1] = f2bf(pp[fr2][fc][1]);
        w[2] = f2bf(pp[fr2][fc][2]); w[3] = f2bf(pp[fr2][fc][3]);
        *(us4*)(&P_lds[q * 40 + 16 * fr2 + 4 * g]) = w;
      }
    }

    // rescale accumulators (row q = 16fq+4g+reg)
    #pragma unroll
    for (int fq = 0; fq < 2; fq++){
      const f32x4 s4 = *(const f32x4*)(&sc_lds[16 * fq + 4 * g]);
      #pragma unroll
      for (int fd = 0; fd < 4; fd++)
        #pragma unroll
        for (int rr = 0; rr < 4; rr++)
          acc[fq][fd][rr] *= s4[rr];
    }

    // PA fragments + PV
    bf16x8 pa[2];
    #pragma unroll
    for (int fq = 0; fq < 2; fq++)
      pa[fq] = *(const bf16x8*)(&P_lds[(r15 + 16 * fq) * 40 + 8 * g]);
    #pragma unroll
    for (int fq = 0; fq < 2; fq++)
      #pragma unroll
      for (int fd = 0; fd < 4; fd++)
        acc[fq][fd] = __builtin_amdgcn_mfma_f32_16x16x32_bf16(pa[fq], vb[fd], acc[fq][fd], 0, 0, 0);
  }

  // epilogue: 1/l then split-bf16 write [hi|hi|lo]
  if (g == 0){
    sc_lds[r15]      = 1.f / lrow[0];
    sc_lds[r15 + 16] = 1.f / lrow[1];
  }
  #pragma unroll
  for (int fq = 0; fq < 2; fq++){
    const f32x4 li = *(const f32x4*)(&sc_lds[16 * fq + 4 * g]);
    #pragma unroll
    for (int rr = 0; rr < 4; rr++){
      const int t = 16 * fq + 4 * g + rr;
      const int i = i_min + 4 * t;
      unsigned short* rowp = AttnP + ((size_t)(b * 2048 + i)) * 3072 + h * 64 + r15;
      #pragma unroll
      for (int fd = 0; fd < 4; fd++){
        const float o = acc[fq][fd][rr] * li[rr];
        const unsigned short hi = f2bf(o);
        const unsigned short lo = f2bf(o - bf2f(hi));
        rowp[16 * fd] = hi;
        rowp[1024 + 16 * fd] = hi;
        rowp[2048 + 16 * fd] = lo;
      }
    }
  }
}

extern "C" void kernel_launch(void* const* d_in, const int* in_sizes, int n_in,
                              void* d_out, int out_size, void* d_ws, size_t ws_size,
                              hipStream_t stream){
  const float* x   = (const float*)d_in[0];
  const float* qkv = (const float*)d_in[1];
  const float* wo  = (const float*)d_in[2];
  float* out = (float*)d_out;

  // workspace layout (84 MB total)
  char* ws = (char*)d_ws;
  const size_t MB = 1024 * 1024;
  unsigned short* Xb    = (unsigned short*)(ws + 0 * MB);   // 8 MB  4096x1024 bf16
  unsigned short* QKVw  = (unsigned short*)(ws + 8 * MB);   // 6 MB  3072x1024 bf16
  unsigned short* Wp    = (unsigned short*)(ws + 14 * MB);  // 6 MB  1024x3072 split
  unsigned short* Qb    = (unsigned short*)(ws + 20 * MB);  // 8 MB  [bh][i][d]
  unsigned short* Kb    = (unsigned short*)(ws + 28 * MB);  // 8 MB  [bh][j][d]
  unsigned short* Kd    = (unsigned short*)(ws + 36 * MB);  // 8 MB  [bh][r][m][d]
  unsigned short* Vt    = (unsigned short*)(ws + 44 * MB);  // 8 MB  [bh][d][j]
  unsigned short* Vtd   = (unsigned short*)(ws + 52 * MB);  // 8 MB  [bh][r][d][m]
  unsigned short* AttnP = (unsigned short*)(ws + 60 * MB);  // 24 MB 4096x3072 split

  cvt_bf16_kernel<<<dim3(4096), dim3(256), 0, stream>>>(x,   Xb,   4096 * 1024 / 4);
  cvt_bf16_kernel<<<dim3(3072), dim3(256), 0, stream>>>(qkv, QKVw, 3072 * 1024 / 4);
  split_kernel<<<dim3(4096), dim3(256), 0, stream>>>(wo, Wp, 1024 * 1024);

  gemm_nt<1024, 1><<<dim3(32, 24), dim3(256), 0, stream>>>(
      Xb, QKVw, (float*)nullptr, 0, Qb, Kb, Kd, Vt, Vtd);

  attn_mfma<<<dim3(64, 32), dim3(64), 0, stream>>>(Qb, Kb, Kd, Vt, Vtd, AttnP);

  gemm_nt<3072, 0><<<dim3(32, 8), dim3(256), 0, stream>>>(
      AttnP, Wp, out, 1024,
      (unsigned short*)nullptr, (unsigned short*)nullptr, (unsigned short*)nullptr,
      (unsigned short*)nullptr, (unsigned short*)nullptr);
}

// Round 4
// 204.007 us; speedup vs baseline: 12.8601x; 1.2869x over previous
//
#include <hip/hip_runtime.h>
#include <hip/hip_bf16.h>

// CustomWindowMHA on MI355X.
// x:(2,2048,1024) f32, qkv:(3072,1024) f32, wo:(1024,1024) f32 -> out:(2,2048,1024) f32
// Pipeline:
//   cvt_all: x,qkv,wo -> bf16
//   GEMM1 (bf16, K=1024, global_load_lds staging): epilogue scatters bf16 Q(*0.125), K,
//         K_dil(residue-compacted), V^T, V^T_dil(residue-compacted)
//   attn: block-sparse MFMA flash attention (1 wave / 32 residue-grouped queries) -> bf16 AttnP
//   GEMM2 (bf16, K=1024) -> out f32

typedef short bf16x8 __attribute__((ext_vector_type(8)));
typedef float f32x4 __attribute__((ext_vector_type(4)));
typedef unsigned short us4 __attribute__((ext_vector_type(4)));

__device__ __forceinline__ unsigned short f2bf(float f){
  unsigned u = __float_as_uint(f);
  u += 0x7FFFu + ((u >> 16) & 1u);           // RNE
  return (unsigned short)(u >> 16);
}
__device__ __forceinline__ float bf2f(unsigned short h){
  return __uint_as_float(((unsigned)h) << 16);
}

// async global->LDS, 16B per lane; LDS dest = wave-uniform base + lane*16 (CK cast idiom)
__device__ __forceinline__ void gload_lds16(const unsigned short* g, unsigned short* s){
  __builtin_amdgcn_global_load_lds(
    (const __attribute__((address_space(1))) unsigned int*)(uintptr_t)(const void*)g,
    (__attribute__((address_space(3))) unsigned int*)(uintptr_t)(void*)s,
    16, 0, 0);
}

// ---------------- fused converts ----------------
// x: 1048576 float4s, qkv: 786432, wo: 262144
__global__ void cvt_all(const float* __restrict__ x, const float* __restrict__ qkv,
                        const float* __restrict__ wo,
                        unsigned short* __restrict__ Xb, unsigned short* __restrict__ QKVw,
                        unsigned short* __restrict__ Wb){
  int idx = blockIdx.x * 256 + threadIdx.x;
  const float* s; unsigned short* d; int off;
  if (idx < 1048576){ s = x; d = Xb; off = idx; }
  else if (idx < 1835008){ s = qkv; d = QKVw; off = idx - 1048576; }
  else { if (idx >= 2097152) return; s = wo; d = Wb; off = idx - 1835008; }
  float4 v = ((const float4*)s)[off];
  us4 o;
  o[0] = f2bf(v.x); o[1] = f2bf(v.y); o[2] = f2bf(v.z); o[3] = f2bf(v.w);
  ((us4*)d)[off] = o;
}

// ---------------- GEMM ----------------
// C[m][n] = sum_k A[m][k]*B[n][k], K=1024, bf16 inputs, f32 accumulate.
// BM=64, BN=128, BK=64; 4 waves (2x2), wave tile 32x64 (frag 2x4).
// LDS 24KB single-buffered, XOR-swizzled (byte ^= (row&7)<<4 on 16B cols),
// staged via global_load_lds with inverse-swizzled per-lane sources.
// EPI=0: plain f32 store to C (ldc=1024). EPI=1: QKV scatter epilogue.
template<int EPI>
__global__ __launch_bounds__(256)
void gemm_nt(const unsigned short* __restrict__ A, const unsigned short* __restrict__ B,
             float* __restrict__ C,
             unsigned short* __restrict__ Qb, unsigned short* __restrict__ Kb,
             unsigned short* __restrict__ Kd, unsigned short* __restrict__ Vt,
             unsigned short* __restrict__ Vtd){
  constexpr int K = 1024;
  __shared__ __align__(16) unsigned short sMem[(64 + 128) * 64];  // 24KB
  char* sAb = (char*)sMem;            // 8KB : A 64 rows x 128B
  char* sBb = (char*)sMem + 8192;     // 16KB: B 128 rows x 128B

  const int tid  = threadIdx.x;
  const int lane = tid & 63;
  const int w    = tid >> 6;
  const int wr = w >> 1, wc = w & 1;
  const int m0 = blockIdx.x * 64;
  const int n0 = blockIdx.y * 128;

  // staging: decode linear LDS slot -> (row, swizzled col) -> global source
  const unsigned short* srcA[2];
  const unsigned short* srcB[4];
  int ldsA[2], ldsB[4];
  #pragma unroll
  for (int q = 0; q < 2; q++){
    int id  = (w * 2 + q) * 1024 + 16 * lane;
    int row = id >> 7;
    int cb  = (id & 127) ^ ((row & 7) << 4);
    srcA[q] = A + (size_t)(m0 + row) * K + (cb >> 1);
    ldsA[q] = (w * 2 + q) * 1024;
  }
  #pragma unroll
  for (int q = 0; q < 4; q++){
    int id  = (w * 4 + q) * 1024 + 16 * lane;
    int row = id >> 7;
    int cb  = (id & 127) ^ ((row & 7) << 4);
    srcB[q] = B + (size_t)(n0 + row) * K + (cb >> 1);
    ldsB[q] = (w * 4 + q) * 1024;
  }

  const int fr = lane & 15;
  const int kg = lane >> 4;
  const int xr = (fr & 7) << 4;
  const int aBase = (wr * 32 + fr) * 128;
  const int bBase = (wc * 64 + fr) * 128;

  f32x4 acc[2][4] = {};

  for (int t = 0; t < K / 64; t++){
    #pragma unroll
    for (int q = 0; q < 2; q++)
      gload_lds16(srcA[q] + t * 64, (unsigned short*)(sAb + ldsA[q]));
    #pragma unroll
    for (int q = 0; q < 4; q++)
      gload_lds16(srcB[q] + t * 64, (unsigned short*)(sBb + ldsB[q]));
    __syncthreads();   // vmcnt drain + barrier: LDS tile ready
    #pragma unroll
    for (int ks = 0; ks < 2; ks++){
      const int cb = (ks * 64 + kg * 16) ^ xr;
      bf16x8 af[2], bfr[4];
      #pragma unroll
      for (int f = 0; f < 2; f++) af[f]  = *(const bf16x8*)(sAb + aBase + f * 2048 + cb);
      #pragma unroll
      for (int f = 0; f < 4; f++) bfr[f] = *(const bf16x8*)(sBb + bBase + f * 2048 + cb);
      #pragma unroll
      for (int fm = 0; fm < 2; fm++)
        #pragma unroll
        for (int fn = 0; fn < 4; fn++)
          acc[fm][fn] = __builtin_amdgcn_mfma_f32_16x16x32_bf16(af[fm], bfr[fn], acc[fm][fn], 0, 0, 0);
    }
    __syncthreads();   // compute done before next overwrite
  }

  // C/D layout: col = lane&15, row = (lane>>4)*4 + reg
  const int crow = wr * 32 + kg * 4;
  const int ccol = wc * 64 + fr;
  if constexpr (EPI == 0){
    #pragma unroll
    for (int fm = 0; fm < 2; fm++)
      #pragma unroll
      for (int fn = 0; fn < 4; fn++)
        #pragma unroll
        for (int i2 = 0; i2 < 4; i2++)
          C[(size_t)(m0 + crow + fm * 16 + i2) * 1024 + n0 + ccol + fn * 16] = acc[fm][fn][i2];
  } else {
    #pragma unroll
    for (int fn = 0; fn < 4; fn++){
      const int nb = n0 + wc * 64 + 16 * fn;        // wave-uniform
      const int which = nb >> 10;                   // 0=Q 1=K 2=V
      const int hh = (nb >> 6) & 15;
      const int d = (nb & 63) + fr;
      #pragma unroll
      for (int fm = 0; fm < 2; fm++)
        #pragma unroll
        for (int i2 = 0; i2 < 4; i2++){
          const int token = m0 + crow + fm * 16 + i2;
          const int btok = token >> 11;
          const int itok = token & 2047;
          const int bhh = btok * 16 + hh;
          const float val = acc[fm][fn][i2];
          if (which == 0){
            Qb[((size_t)bhh * 2048 + itok) * 64 + d] = f2bf(val * 0.125f);
          } else if (which == 1){
            const unsigned short v = f2bf(val);
            Kb[((size_t)bhh * 2048 + itok) * 64 + d] = v;
            Kd[(((size_t)bhh * 4 + (itok & 3)) * 512 + (itok >> 2)) * 64 + d] = v;
          } else {
            const unsigned short v = f2bf(val);
            Vt[((size_t)bhh * 64 + d) * 2048 + itok] = v;
            Vtd[(((size_t)bhh * 4 + (itok & 3)) * 64 + d) * 512 + (itok >> 2)] = v;
          }
        }
    }
  }
}

// ---------------- block-sparse MFMA flash attention ----------------
// One wave per (b,h, residue c, group gq): 32 queries i = c + 128*gq + 4*t.
__global__ __launch_bounds__(64)
void attn_mfma(const unsigned short* __restrict__ Qb,
               const unsigned short* __restrict__ Kb,
               const unsigned short* __restrict__ Kd,
               const unsigned short* __restrict__ Vt,
               const unsigned short* __restrict__ Vtd,
               unsigned short* __restrict__ AttnP){
  const int lane = threadIdx.x;
  const int r15 = lane & 15;
  const int g   = lane >> 4;
  const int c   = blockIdx.x & 3;
  const int gq  = 15 - (blockIdx.x >> 2);   // heavy blocks first
  const int bh  = blockIdx.y;
  const int b   = bh >> 4;
  const int h   = bh & 15;

  __shared__ __align__(16) unsigned short P_lds[32 * 40];
  __shared__ __align__(16) float sc_lds[32];

  const int i_min = c + 128 * gq;

  const unsigned short* Qb_b  = Qb  + (size_t)bh * 2048 * 64;
  const unsigned short* Kb_b  = Kb  + (size_t)bh * 2048 * 64;
  const unsigned short* Vt_b  = Vt  + (size_t)bh * 64 * 2048;
  const unsigned short* Kd_b  = Kd  + ((size_t)bh * 4 + c) * (512 * 64);
  const unsigned short* Vtd_b = Vtd + ((size_t)bh * 4 + c) * (64 * 512);

  bf16x8 qf[2][2];
  #pragma unroll
  for (int fc = 0; fc < 2; fc++){
    const int i = i_min + 4 * (r15 + 16 * fc);
    #pragma unroll
    for (int kc = 0; kc < 2; kc++)
      qf[fc][kc] = *(const bf16x8*)(Qb_b + (size_t)i * 64 + 32 * kc + 8 * g);
  }

  float mrow[2] = {-1e30f, -1e30f};
  float lrow[2] = {0.f, 0.f};
  f32x4 acc[2][4] = {};

  const int jt0 = (i_min > 127) ? ((i_min - 127) >> 5) : 0;
  const int jt1 = (i_min + 124) >> 5;
  const int ntiles = gq + (jt1 - jt0 + 1);

  for (int tt = 0; tt < ntiles; tt++){
    const bool dil = (tt < gq);
    bf16x8 ka[2][2], vb[4];
    int kbase;
    if (dil){
      const int mb0 = 32 * tt;
      kbase = mb0;
      #pragma unroll
      for (int fr2 = 0; fr2 < 2; fr2++){
        const size_t row = (size_t)(mb0 + 16 * fr2 + r15);
        #pragma unroll
        for (int kc = 0; kc < 2; kc++)
          ka[fr2][kc] = *(const bf16x8*)(Kd_b + row * 64 + 32 * kc + 8 * g);
      }
      #pragma unroll
      for (int fd = 0; fd < 4; fd++)
        vb[fd] = *(const bf16x8*)(Vtd_b + (size_t)(r15 + 16 * fd) * 512 + mb0 + 8 * g);
    } else {
      const int j0 = 32 * (jt0 + tt - gq);
      kbase = j0;
      #pragma unroll
      for (int fr2 = 0; fr2 < 2; fr2++){
        const size_t row = (size_t)(j0 + 16 * fr2 + r15);
        #pragma unroll
        for (int kc = 0; kc < 2; kc++)
          ka[fr2][kc] = *(const bf16x8*)(Kb_b + row * 64 + 32 * kc + 8 * g);
      }
      #pragma unroll
      for (int fd = 0; fd < 4; fd++)
        vb[fd] = *(const bf16x8*)(Vt_b + (size_t)(r15 + 16 * fd) * 2048 + j0 + 8 * g);
    }

    f32x4 sf[2][2];
    #pragma unroll
    for (int fr2 = 0; fr2 < 2; fr2++)
      #pragma unroll
      for (int fc = 0; fc < 2; fc++){
        f32x4 z = {0.f, 0.f, 0.f, 0.f};
        z = __builtin_amdgcn_mfma_f32_16x16x32_bf16(ka[fr2][0], qf[fc][0], z, 0, 0, 0);
        z = __builtin_amdgcn_mfma_f32_16x16x32_bf16(ka[fr2][1], qf[fc][1], z, 0, 0, 0);
        sf[fr2][fc] = z;
      }

    const bool needmask = dil ? (tt == gq - 1) : true;
    if (needmask){
      #pragma unroll
      for (int fr2 = 0; fr2 < 2; fr2++)
        #pragma unroll
        for (int rr = 0; rr < 4; rr++){
          const int kl = kbase + 16 * fr2 + 4 * g + rr;
          #pragma unroll
          for (int fc = 0; fc < 2; fc++){
            const int t = r15 + 16 * fc;
            bool ok;
            if (dil) ok = (kl <= 32 * gq + t - 33);
            else { const int i = i_min + 4 * t; ok = (kl <= i) && (kl >= i - 127); }
            if (!ok) sf[fr2][fc][rr] = -1e30f;
          }
        }
    }

    float pp[2][2][4];
    #pragma unroll
    for (int fc = 0; fc < 2; fc++){
      float mx = sf[0][fc][0];
      #pragma unroll
      for (int fr2 = 0; fr2 < 2; fr2++)
        #pragma unroll
        for (int rr = 0; rr < 4; rr++) mx = fmaxf(mx, sf[fr2][fc][rr]);
      mx = fmaxf(mx, __shfl_xor(mx, 16));
      mx = fmaxf(mx, __shfl_xor(mx, 32));
      const float mn = fmaxf(mrow[fc], mx);
      const float kill = (mn > -1e29f) ? 1.f : 0.f;
      const float scf = __expf(mrow[fc] - mn);
      mrow[fc] = mn;
      float rs = 0.f;
      #pragma unroll
      for (int fr2 = 0; fr2 < 2; fr2++)
        #pragma unroll
        for (int rr = 0; rr < 4; rr++){
          const float pv = __expf(sf[fr2][fc][rr] - mn) * kill;
          pp[fr2][fc][rr] = pv;
          rs += pv;
        }
      rs += __shfl_xor(rs, 16);
      rs += __shfl_xor(rs, 32);
      lrow[fc] = lrow[fc] * scf + rs;
      if (g == 0) sc_lds[r15 + 16 * fc] = scf;
    }

    #pragma unroll
    for (int fc = 0; fc < 2; fc++){
      const int q = r15 + 16 * fc;
      #pragma unroll
      for (int fr2 = 0; fr2 < 2; fr2++){
        us4 wv;
        wv[0] = f2bf(pp[fr2][fc][0]); wv[1] = f2bf(pp[fr2][fc][1]);
        wv[2] = f2bf(pp[fr2][fc][2]); wv[3] = f2bf(pp[fr2][fc][3]);
        *(us4*)(&P_lds[q * 40 + 16 * fr2 + 4 * g]) = wv;
      }
    }

    #pragma unroll
    for (int fq = 0; fq < 2; fq++){
      const f32x4 s4 = *(const f32x4*)(&sc_lds[16 * fq + 4 * g]);
      #pragma unroll
      for (int fd = 0; fd < 4; fd++)
        #pragma unroll
        for (int rr = 0; rr < 4; rr++)
          acc[fq][fd][rr] *= s4[rr];
    }

    bf16x8 pa[2];
    #pragma unroll
    for (int fq = 0; fq < 2; fq++)
      pa[fq] = *(const bf16x8*)(&P_lds[(r15 + 16 * fq) * 40 + 8 * g]);
    #pragma unroll
    for (int fq = 0; fq < 2; fq++)
      #pragma unroll
      for (int fd = 0; fd < 4; fd++)
        acc[fq][fd] = __builtin_amdgcn_mfma_f32_16x16x32_bf16(pa[fq], vb[fd], acc[fq][fd], 0, 0, 0);
  }

  if (g == 0){
    sc_lds[r15]      = 1.f / lrow[0];
    sc_lds[r15 + 16] = 1.f / lrow[1];
  }
  #pragma unroll
  for (int fq = 0; fq < 2; fq++){
    const f32x4 li = *(const f32x4*)(&sc_lds[16 * fq + 4 * g]);
    #pragma unroll
    for (int rr = 0; rr < 4; rr++){
      const int t = 16 * fq + 4 * g + rr;
      const int i = i_min + 4 * t;
      unsigned short* rowp = AttnP + ((size_t)(b * 2048 + i)) * 1024 + h * 64 + r15;
      #pragma unroll
      for (int fd = 0; fd < 4; fd++)
        rowp[16 * fd] = f2bf(acc[fq][fd][rr] * li[rr]);
    }
  }
}

extern "C" void kernel_launch(void* const* d_in, const int* in_sizes, int n_in,
                              void* d_out, int out_size, void* d_ws, size_t ws_size,
                              hipStream_t stream){
  const float* x   = (const float*)d_in[0];
  const float* qkv = (const float*)d_in[1];
  const float* wo  = (const float*)d_in[2];
  float* out = (float*)d_out;

  char* ws = (char*)d_ws;
  const size_t MB = 1024 * 1024;
  unsigned short* Xb    = (unsigned short*)(ws + 0 * MB);   // 8 MB  4096x1024 bf16
  unsigned short* QKVw  = (unsigned short*)(ws + 8 * MB);   // 6 MB  3072x1024 bf16
  unsigned short* Wb    = (unsigned short*)(ws + 14 * MB);  // 2 MB  1024x1024 bf16
  unsigned short* Qb    = (unsigned short*)(ws + 16 * MB);  // 8 MB  [bh][i][d]
  unsigned short* Kb    = (unsigned short*)(ws + 24 * MB);  // 8 MB  [bh][j][d]
  unsigned short* Kd    = (unsigned short*)(ws + 32 * MB);  // 8 MB  [bh][r][m][d]
  unsigned short* Vt    = (unsigned short*)(ws + 40 * MB);  // 8 MB  [bh][d][j]
  unsigned short* Vtd   = (unsigned short*)(ws + 48 * MB);  // 8 MB  [bh][r][d][m]
  unsigned short* AttnP = (unsigned short*)(ws + 56 * MB);  // 8 MB  4096x1024 bf16

  cvt_all<<<dim3(8192), dim3(256), 0, stream>>>(x, qkv, wo, Xb, QKVw, Wb);

  gemm_nt<1><<<dim3(64, 24), dim3(256), 0, stream>>>(
      Xb, QKVw, (float*)nullptr, Qb, Kb, Kd, Vt, Vtd);

  attn_mfma<<<dim3(64, 32), dim3(64), 0, stream>>>(Qb, Kb, Kd, Vt, Vtd, AttnP);

  gemm_nt<0><<<dim3(64, 8), dim3(256), 0, stream>>>(
      AttnP, Wb, out,
      (unsigned short*)nullptr, (unsigned short*)nullptr, (unsigned short*)nullptr,
      (unsigned short*)nullptr, (unsigned short*)nullptr);
}

// Round 5
// 200.247 us; speedup vs baseline: 13.1015x; 1.0188x over previous
//
#include <hip/hip_runtime.h>
#include <hip/hip_bf16.h>

// CustomWindowMHA on MI355X.
// x:(2,2048,1024) f32, qkv:(3072,1024) f32, wo:(1024,1024) f32 -> out:(2,2048,1024) f32
// Pipeline:
//   cvt_all: x,qkv,wo -> bf16
//   gemm_qkv (128x128 tile, m97 structure, gload_lds): epilogue scatters bf16 Q(*0.125), K,
//         K_dil(residue-compacted), V^T, V^T_dil(residue-compacted)
//   attn_mfma: block-sparse MFMA flash attention -> bf16 AttnP
//   gemm_out (64x128, double-buffered counted-vmcnt pipeline) -> out f32

typedef short bf16x8 __attribute__((ext_vector_type(8)));
typedef float f32x4 __attribute__((ext_vector_type(4)));
typedef unsigned short us4 __attribute__((ext_vector_type(4)));

__device__ __forceinline__ unsigned short f2bf(float f){
  unsigned u = __float_as_uint(f);
  u += 0x7FFFu + ((u >> 16) & 1u);           // RNE
  return (unsigned short)(u >> 16);
}
__device__ __forceinline__ float bf2f(unsigned short h){
  return __uint_as_float(((unsigned)h) << 16);
}

// async global->LDS, 16B per lane; LDS dest = wave-uniform base + lane*16
__device__ __forceinline__ void gload_lds16(const unsigned short* g, unsigned short* s){
  __builtin_amdgcn_global_load_lds(
    (const __attribute__((address_space(1))) unsigned int*)(uintptr_t)(const void*)g,
    (__attribute__((address_space(3))) unsigned int*)(uintptr_t)(void*)s,
    16, 0, 0);
}

// ---------------- fused converts ----------------
__global__ void cvt_all(const float* __restrict__ x, const float* __restrict__ qkv,
                        const float* __restrict__ wo,
                        unsigned short* __restrict__ Xb, unsigned short* __restrict__ QKVw,
                        unsigned short* __restrict__ Wb){
  int idx = blockIdx.x * 256 + threadIdx.x;
  const float* s; unsigned short* d; int off;
  if (idx < 1048576){ s = x; d = Xb; off = idx; }
  else if (idx < 1835008){ s = qkv; d = QKVw; off = idx - 1048576; }
  else { if (idx >= 2097152) return; s = wo; d = Wb; off = idx - 1835008; }
  float4 v = ((const float4*)s)[off];
  us4 o;
  o[0] = f2bf(v.x); o[1] = f2bf(v.y); o[2] = f2bf(v.z); o[3] = f2bf(v.w);
  ((us4*)d)[off] = o;
}

// ---------------- GEMM1: 128x128 m97 structure + QKV scatter epilogue ----------------
__global__ __launch_bounds__(256)
void gemm_qkv(const unsigned short* __restrict__ A, const unsigned short* __restrict__ B,
              unsigned short* __restrict__ Qb, unsigned short* __restrict__ Kb,
              unsigned short* __restrict__ Kd, unsigned short* __restrict__ Vt,
              unsigned short* __restrict__ Vtd){
  constexpr int K = 1024;
  __shared__ __align__(16) unsigned short sMem[2 * 128 * 64];  // 32KB
  char* sAb = (char*)sMem;              // 16KB: A 128 rows x 128B
  char* sBb = (char*)sMem + 16384;      // 16KB: B 128 rows x 128B

  const int tid  = threadIdx.x;
  const int lane = tid & 63;
  const int w    = tid >> 6;
  const int wr = w >> 1, wc = w & 1;
  const int m0 = blockIdx.x * 128;
  const int n0 = blockIdx.y * 128;

  // staging decode: linear LDS slot -> (row, swizzled col) -> global source
  const unsigned short* srcA[4];
  const unsigned short* srcB[4];
  int ldsOff[4];
  #pragma unroll
  for (int q = 0; q < 4; q++){
    int id  = (q * 4 + w) * 1024 + 16 * lane;
    int row = id >> 7;
    int cb  = (id & 127) ^ ((row & 7) << 4);
    srcA[q] = A + (size_t)(m0 + row) * K + (cb >> 1);
    srcB[q] = B + (size_t)(n0 + row) * K + (cb >> 1);
    ldsOff[q] = (q * 4 + w) * 1024;
  }

  const int fr = lane & 15;
  const int kg = lane >> 4;
  const int xr = (fr & 7) << 4;
  const int aBase = (wr * 64 + fr) * 128;
  const int bBase = (wc * 64 + fr) * 128;

  f32x4 acc[4][4] = {};

  for (int t = 0; t < K / 64; t++){
    #pragma unroll
    for (int q = 0; q < 4; q++){
      gload_lds16(srcA[q] + t * 64, (unsigned short*)(sAb + ldsOff[q]));
      gload_lds16(srcB[q] + t * 64, (unsigned short*)(sBb + ldsOff[q]));
    }
    __syncthreads();
    #pragma unroll
    for (int ks = 0; ks < 2; ks++){
      const int cb = (ks * 64 + kg * 16) ^ xr;
      bf16x8 af[4], bfr[4];
      #pragma unroll
      for (int f = 0; f < 4; f++){
        af[f]  = *(const bf16x8*)(sAb + aBase + f * 2048 + cb);
        bfr[f] = *(const bf16x8*)(sBb + bBase + f * 2048 + cb);
      }
      #pragma unroll
      for (int fm = 0; fm < 4; fm++)
        #pragma unroll
        for (int fn = 0; fn < 4; fn++)
          acc[fm][fn] = __builtin_amdgcn_mfma_f32_16x16x32_bf16(af[fm], bfr[fn], acc[fm][fn], 0, 0, 0);
    }
    __syncthreads();
  }

  // scatter epilogue; C/D layout: col = lane&15, row = (lane>>4)*4 + reg
  const int crow = wr * 64 + kg * 4;
  #pragma unroll
  for (int fn = 0; fn < 4; fn++){
    const int nb = n0 + wc * 64 + 16 * fn;          // wave-uniform
    const int which = nb >> 10;                     // 0=Q 1=K 2=V
    const int hh = (nb >> 6) & 15;
    const int d = (nb & 63) + fr;
    #pragma unroll
    for (int fm = 0; fm < 4; fm++){
      const int token0 = m0 + crow + fm * 16;      // multiple of 4
      const int btok  = token0 >> 11;
      const int itok0 = token0 & 2047;
      const int bhh   = btok * 16 + hh;
      if (which == 0){
        #pragma unroll
        for (int i2 = 0; i2 < 4; i2++)
          Qb[((size_t)bhh * 2048 + itok0 + i2) * 64 + d] = f2bf(acc[fm][fn][i2] * 0.125f);
      } else if (which == 1){
        #pragma unroll
        for (int i2 = 0; i2 < 4; i2++){
          const int itok = itok0 + i2;
          const unsigned short v = f2bf(acc[fm][fn][i2]);
          Kb[((size_t)bhh * 2048 + itok) * 64 + d] = v;
          Kd[(((size_t)bhh * 4 + (itok & 3)) * 512 + (itok >> 2)) * 64 + d] = v;
        }
      } else {
        us4 pv;
        #pragma unroll
        for (int i2 = 0; i2 < 4; i2++) pv[i2] = f2bf(acc[fm][fn][i2]);
        *(us4*)(Vt + ((size_t)bhh * 64 + d) * 2048 + itok0) = pv;   // 4 tok-consecutive
        #pragma unroll
        for (int i2 = 0; i2 < 4; i2++){
          const int itok = itok0 + i2;
          Vtd[((size_t)bhh * 4 + (itok & 3)) * 32768 + (size_t)d * 512 + (itok >> 2)] = pv[i2];
        }
      }
    }
  }
}

// ---------------- GEMM2: 64x128, double-buffered counted-vmcnt pipeline ----------------
__global__ __launch_bounds__(256)
void gemm_out(const unsigned short* __restrict__ A, const unsigned short* __restrict__ B,
              float* __restrict__ C){
  constexpr int K = 1024;
  __shared__ __align__(16) unsigned short sMem[2 * (64 + 128) * 64];  // 48KB, 2 buffers
  char* base0 = (char*)sMem;   // buffer p at p*24576; A at +0 (8KB), B at +8192 (16KB)

  const int tid  = threadIdx.x;
  const int lane = tid & 63;
  const int w    = tid >> 6;
  const int wr = w >> 1, wc = w & 1;
  const int m0 = blockIdx.x * 64;
  const int n0 = blockIdx.y * 128;

  const unsigned short* srcA[2];
  const unsigned short* srcB[4];
  int ldsA[2], ldsB[4];
  #pragma unroll
  for (int q = 0; q < 2; q++){
    int id  = (q * 4 + w) * 1024 + 16 * lane;
    int row = id >> 7;
    int cb  = (id & 127) ^ ((row & 7) << 4);
    srcA[q] = A + (size_t)(m0 + row) * K + (cb >> 1);
    ldsA[q] = (q * 4 + w) * 1024;
  }
  #pragma unroll
  for (int q = 0; q < 4; q++){
    int id  = (q * 4 + w) * 1024 + 16 * lane;
    int row = id >> 7;
    int cb  = (id & 127) ^ ((row & 7) << 4);
    srcB[q] = B + (size_t)(n0 + row) * K + (cb >> 1);
    ldsB[q] = (q * 4 + w) * 1024;
  }

  const int fr = lane & 15;
  const int kg = lane >> 4;
  const int xr = (fr & 7) << 4;
  const int aBase = (wr * 32 + fr) * 128;
  const int bBase = (wc * 64 + fr) * 128;

  f32x4 acc[2][4] = {};

  // prologue: stage tile 0 into buffer 0 (6 loads in flight)
  #pragma unroll
  for (int q = 0; q < 2; q++) gload_lds16(srcA[q], (unsigned short*)(base0 + ldsA[q]));
  #pragma unroll
  for (int q = 0; q < 4; q++) gload_lds16(srcB[q], (unsigned short*)(base0 + 8192 + ldsB[q]));

  int cur = 0;
  for (int t = 0; t < 16; t++){
    char* bcur = base0 + cur * 24576;
    if (t < 15){
      char* bnxt = base0 + (cur ^ 1) * 24576;   // prev-prev buffer: reads done at last barrier
      #pragma unroll
      for (int q = 0; q < 2; q++) gload_lds16(srcA[q] + (t + 1) * 64, (unsigned short*)(bnxt + ldsA[q]));
      #pragma unroll
      for (int q = 0; q < 4; q++) gload_lds16(srcB[q] + (t + 1) * 64, (unsigned short*)(bnxt + 8192 + ldsB[q]));
      __builtin_amdgcn_sched_barrier(0);
      asm volatile("s_waitcnt vmcnt(6)");      // wait current tile only; next 6 stay in flight
    } else {
      __builtin_amdgcn_sched_barrier(0);
      asm volatile("s_waitcnt vmcnt(0)");
    }
    __builtin_amdgcn_s_barrier();              // raw barrier: no vmcnt(0) auto-drain
    __builtin_amdgcn_sched_barrier(0);
    #pragma unroll
    for (int ks = 0; ks < 2; ks++){
      const int cb = (ks * 64 + kg * 16) ^ xr;
      bf16x8 af[2], bfr[4];
      #pragma unroll
      for (int f = 0; f < 2; f++) af[f]  = *(const bf16x8*)(bcur + aBase + f * 2048 + cb);
      #pragma unroll
      for (int f = 0; f < 4; f++) bfr[f] = *(const bf16x8*)(bcur + 8192 + bBase + f * 2048 + cb);
      #pragma unroll
      for (int fm = 0; fm < 2; fm++)
        #pragma unroll
        for (int fn = 0; fn < 4; fn++)
          acc[fm][fn] = __builtin_amdgcn_mfma_f32_16x16x32_bf16(af[fm], bfr[fn], acc[fm][fn], 0, 0, 0);
    }
    asm volatile("s_waitcnt lgkmcnt(0)" ::: "memory");  // ds_reads landed in regs
    __builtin_amdgcn_sched_barrier(0);                  // rule 18: pin order
    __builtin_amdgcn_s_barrier();                       // all waves done reading bcur
    cur ^= 1;
  }

  const int crow = wr * 32 + kg * 4;
  const int ccol = wc * 64 + fr;
  #pragma unroll
  for (int fm = 0; fm < 2; fm++)
    #pragma unroll
    for (int fn = 0; fn < 4; fn++)
      #pragma unroll
      for (int i2 = 0; i2 < 4; i2++)
        C[(size_t)(m0 + crow + fm * 16 + i2) * 1024 + n0 + ccol + fn * 16] = acc[fm][fn][i2];
}

// ---------------- block-sparse MFMA flash attention ----------------
__global__ __launch_bounds__(64)
void attn_mfma(const unsigned short* __restrict__ Qb,
               const unsigned short* __restrict__ Kb,
               const unsigned short* __restrict__ Kd,
               const unsigned short* __restrict__ Vt,
               const unsigned short* __restrict__ Vtd,
               unsigned short* __restrict__ AttnP){
  const int lane = threadIdx.x;
  const int r15 = lane & 15;
  const int g   = lane >> 4;
  const int c   = blockIdx.x & 3;
  const int gq  = 15 - (blockIdx.x >> 2);   // heavy blocks first
  const int bh  = blockIdx.y;
  const int b   = bh >> 4;
  const int h   = bh & 15;

  __shared__ __align__(16) unsigned short P_lds[32 * 40];
  __shared__ __align__(16) float sc_lds[32];

  const int i_min = c + 128 * gq;

  const unsigned short* Qb_b  = Qb  + (size_t)bh * 2048 * 64;
  const unsigned short* Kb_b  = Kb  + (size_t)bh * 2048 * 64;
  const unsigned short* Vt_b  = Vt  + (size_t)bh * 64 * 2048;
  const unsigned short* Kd_b  = Kd  + ((size_t)bh * 4 + c) * (512 * 64);
  const unsigned short* Vtd_b = Vtd + ((size_t)bh * 4 + c) * (64 * 512);

  bf16x8 qf[2][2];
  #pragma unroll
  for (int fc = 0; fc < 2; fc++){
    const int i = i_min + 4 * (r15 + 16 * fc);
    #pragma unroll
    for (int kc = 0; kc < 2; kc++)
      qf[fc][kc] = *(const bf16x8*)(Qb_b + (size_t)i * 64 + 32 * kc + 8 * g);
  }

  float mrow[2] = {-1e30f, -1e30f};
  float lrow[2] = {0.f, 0.f};
  f32x4 acc[2][4] = {};

  const int jt0 = (i_min > 127) ? ((i_min - 127) >> 5) : 0;
  const int jt1 = (i_min + 124) >> 5;
  const int ntiles = gq + (jt1 - jt0 + 1);

  for (int tt = 0; tt < ntiles; tt++){
    const bool dil = (tt < gq);
    bf16x8 ka[2][2], vb[4];
    int kbase;
    if (dil){
      const int mb0 = 32 * tt;
      kbase = mb0;
      #pragma unroll
      for (int fr2 = 0; fr2 < 2; fr2++){
        const size_t row = (size_t)(mb0 + 16 * fr2 + r15);
        #pragma unroll
        for (int kc = 0; kc < 2; kc++)
          ka[fr2][kc] = *(const bf16x8*)(Kd_b + row * 64 + 32 * kc + 8 * g);
      }
      #pragma unroll
      for (int fd = 0; fd < 4; fd++)
        vb[fd] = *(const bf16x8*)(Vtd_b + (size_t)(r15 + 16 * fd) * 512 + mb0 + 8 * g);
    } else {
      const int j0 = 32 * (jt0 + tt - gq);
      kbase = j0;
      #pragma unroll
      for (int fr2 = 0; fr2 < 2; fr2++){
        const size_t row = (size_t)(j0 + 16 * fr2 + r15);
        #pragma unroll
        for (int kc = 0; kc < 2; kc++)
          ka[fr2][kc] = *(const bf16x8*)(Kb_b + row * 64 + 32 * kc + 8 * g);
      }
      #pragma unroll
      for (int fd = 0; fd < 4; fd++)
        vb[fd] = *(const bf16x8*)(Vt_b + (size_t)(r15 + 16 * fd) * 2048 + j0 + 8 * g);
    }

    f32x4 sf[2][2];
    #pragma unroll
    for (int fr2 = 0; fr2 < 2; fr2++)
      #pragma unroll
      for (int fc = 0; fc < 2; fc++){
        f32x4 z = {0.f, 0.f, 0.f, 0.f};
        z = __builtin_amdgcn_mfma_f32_16x16x32_bf16(ka[fr2][0], qf[fc][0], z, 0, 0, 0);
        z = __builtin_amdgcn_mfma_f32_16x16x32_bf16(ka[fr2][1], qf[fc][1], z, 0, 0, 0);
        sf[fr2][fc] = z;
      }

    const bool needmask = dil ? (tt == gq - 1) : true;
    if (needmask){
      #pragma unroll
      for (int fr2 = 0; fr2 < 2; fr2++)
        #pragma unroll
        for (int rr = 0; rr < 4; rr++){
          const int kl = kbase + 16 * fr2 + 4 * g + rr;
          #pragma unroll
          for (int fc = 0; fc < 2; fc++){
            const int t = r15 + 16 * fc;
            bool ok;
            if (dil) ok = (kl <= 32 * gq + t - 33);
            else { const int i = i_min + 4 * t; ok = (kl <= i) && (kl >= i - 127); }
            if (!ok) sf[fr2][fc][rr] = -1e30f;
          }
        }
    }

    float pp[2][2][4];
    #pragma unroll
    for (int fc = 0; fc < 2; fc++){
      float mx = sf[0][fc][0];
      #pragma unroll
      for (int fr2 = 0; fr2 < 2; fr2++)
        #pragma unroll
        for (int rr = 0; rr < 4; rr++) mx = fmaxf(mx, sf[fr2][fc][rr]);
      mx = fmaxf(mx, __shfl_xor(mx, 16));
      mx = fmaxf(mx, __shfl_xor(mx, 32));
      const float mn = fmaxf(mrow[fc], mx);
      const float kill = (mn > -1e29f) ? 1.f : 0.f;
      const float scf = __expf(mrow[fc] - mn);
      mrow[fc] = mn;
      float rs = 0.f;
      #pragma unroll
      for (int fr2 = 0; fr2 < 2; fr2++)
        #pragma unroll
        for (int rr = 0; rr < 4; rr++){
          const float pv = __expf(sf[fr2][fc][rr] - mn) * kill;
          pp[fr2][fc][rr] = pv;
          rs += pv;
        }
      rs += __shfl_xor(rs, 16);
      rs += __shfl_xor(rs, 32);
      lrow[fc] = lrow[fc] * scf + rs;
      if (g == 0) sc_lds[r15 + 16 * fc] = scf;
    }

    #pragma unroll
    for (int fc = 0; fc < 2; fc++){
      const int q = r15 + 16 * fc;
      #pragma unroll
      for (int fr2 = 0; fr2 < 2; fr2++){
        us4 wv;
        wv[0] = f2bf(pp[fr2][fc][0]); wv[1] = f2bf(pp[fr2][fc][1]);
        wv[2] = f2bf(pp[fr2][fc][2]); wv[3] = f2bf(pp[fr2][fc][3]);
        *(us4*)(&P_lds[q * 40 + 16 * fr2 + 4 * g]) = wv;
      }
    }

    #pragma unroll
    for (int fq = 0; fq < 2; fq++){
      const f32x4 s4 = *(const f32x4*)(&sc_lds[16 * fq + 4 * g]);
      #pragma unroll
      for (int fd = 0; fd < 4; fd++)
        #pragma unroll
        for (int rr = 0; rr < 4; rr++)
          acc[fq][fd][rr] *= s4[rr];
    }

    bf16x8 pa[2];
    #pragma unroll
    for (int fq = 0; fq < 2; fq++)
      pa[fq] = *(const bf16x8*)(&P_lds[(r15 + 16 * fq) * 40 + 8 * g]);
    #pragma unroll
    for (int fq = 0; fq < 2; fq++)
      #pragma unroll
      for (int fd = 0; fd < 4; fd++)
        acc[fq][fd] = __builtin_amdgcn_mfma_f32_16x16x32_bf16(pa[fq], vb[fd], acc[fq][fd], 0, 0, 0);
  }

  if (g == 0){
    sc_lds[r15]      = 1.f / lrow[0];
    sc_lds[r15 + 16] = 1.f / lrow[1];
  }
  #pragma unroll
  for (int fq = 0; fq < 2; fq++){
    const f32x4 li = *(const f32x4*)(&sc_lds[16 * fq + 4 * g]);
    #pragma unroll
    for (int rr = 0; rr < 4; rr++){
      const int t = 16 * fq + 4 * g + rr;
      const int i = i_min + 4 * t;
      unsigned short* rowp = AttnP + ((size_t)(b * 2048 + i)) * 1024 + h * 64 + r15;
      #pragma unroll
      for (int fd = 0; fd < 4; fd++)
        rowp[16 * fd] = f2bf(acc[fq][fd][rr] * li[rr]);
    }
  }
}

extern "C" void kernel_launch(void* const* d_in, const int* in_sizes, int n_in,
                              void* d_out, int out_size, void* d_ws, size_t ws_size,
                              hipStream_t stream){
  const float* x   = (const float*)d_in[0];
  const float* qkv = (const float*)d_in[1];
  const float* wo  = (const float*)d_in[2];
  float* out = (float*)d_out;

  char* ws = (char*)d_ws;
  const size_t MB = 1024 * 1024;
  unsigned short* Xb    = (unsigned short*)(ws + 0 * MB);   // 8 MB  4096x1024 bf16
  unsigned short* QKVw  = (unsigned short*)(ws + 8 * MB);   // 6 MB  3072x1024 bf16
  unsigned short* Wb    = (unsigned short*)(ws + 14 * MB);  // 2 MB  1024x1024 bf16
  unsigned short* Qb    = (unsigned short*)(ws + 16 * MB);  // 8 MB  [bh][i][d]
  unsigned short* Kb    = (unsigned short*)(ws + 24 * MB);  // 8 MB  [bh][j][d]
  unsigned short* Kd    = (unsigned short*)(ws + 32 * MB);  // 8 MB  [bh][r][m][d]
  unsigned short* Vt    = (unsigned short*)(ws + 40 * MB);  // 8 MB  [bh][d][j]
  unsigned short* Vtd   = (unsigned short*)(ws + 48 * MB);  // 8 MB  [bh][r][d][m]
  unsigned short* AttnP = (unsigned short*)(ws + 56 * MB);  // 8 MB  4096x1024 bf16

  cvt_all<<<dim3(8192), dim3(256), 0, stream>>>(x, qkv, wo, Xb, QKVw, Wb);

  gemm_qkv<<<dim3(32, 24), dim3(256), 0, stream>>>(Xb, QKVw, Qb, Kb, Kd, Vt, Vtd);

  attn_mfma<<<dim3(64, 32), dim3(64), 0, stream>>>(Qb, Kb, Kd, Vt, Vtd, AttnP);

  gemm_out<<<dim3(64, 8), dim3(256), 0, stream>>>(AttnP, Wb, out);
}